// Round 3
// baseline (2416.692 us; speedup 1.0000x reference)
//
#include <hip/hip_runtime.h>

#define DD 512
#define BB 256
#define SS 128
#define N3 1536
#define CHUNK 16          // timesteps per G-chunk
#define MCH (BB*CHUNK)    // 4096 rows per chunk gemm
#define MTOT (BB*SS)      // 32768

typedef __bf16 bf16;
typedef float f32x4 __attribute__((ext_vector_type(4)));
typedef __bf16 bf16x8 __attribute__((ext_vector_type(8)));

__device__ __forceinline__ float sigm(float z){ return 1.f/(1.f+__expf(-z)); }

// ---- transpose six 512x512 fp32 matrices into bf16: dst[n][k] = src[k][n] ----
__global__ void k_transpose(const float* __restrict__ s0,const float* __restrict__ s1,
                            const float* __restrict__ s2,const float* __restrict__ s3,
                            const float* __restrict__ s4,const float* __restrict__ s5,
                            bf16* __restrict__ wt, bf16* __restrict__ ut){
  __shared__ float tile[32][33];
  int z = blockIdx.z;
  const float* src = z==0?s0:z==1?s1:z==2?s2:z==3?s3:z==4?s4:s5;
  bf16* dst = (z<3)? (wt + (size_t)z*DD*DD) : (ut + (size_t)(z-3)*DD*DD);
  int bx = blockIdx.x*32, by = blockIdx.y*32;
  int tx = threadIdx.x, ty = threadIdx.y;   // 32 x 8
  for (int i=0;i<32;i+=8) tile[ty+i][tx] = src[(size_t)(by+ty+i)*DD + bx+tx];
  __syncthreads();
  for (int i=0;i<32;i+=8) dst[(size_t)(bx+ty+i)*DD + by+tx] = (bf16)tile[tx][ty+i];
}

// ---- init h buffers from fp32 h0 ----
__global__ void k_init(const float* __restrict__ h0, float* __restrict__ hf0, float* __restrict__ hf1,
                       bf16* __restrict__ hb0, bf16* __restrict__ hb1){
  int i = blockIdx.x*256 + threadIdx.x;
  float v = h0[i];
  hf0[i] = v; hf1[i] = v;
  bf16 b = (bf16)v;
  hb0[i] = b; hb1[i] = b;
}

// ---- convert one chunk of X (fp32, row b*S+t) to bf16 Xc (row b*CHUNK+tt) ----
__global__ __launch_bounds__(256) void k_cvt(const float* __restrict__ X, bf16* __restrict__ Xc, int c16){
  int tid = blockIdx.x*256 + threadIdx.x;      // total MCH*DD/8 threads
  int e0 = tid*8;
  int mg = e0 >> 9;            // chunk-local row (b*CHUNK+tt)
  int k  = e0 & 511;
  int xrow = ((mg>>4)*SS) + c16 + (mg&15);     // global x row b*S + t
  const float* p = X + (size_t)xrow*DD + k;
  float4 va = *reinterpret_cast<const float4*>(p);
  float4 vb = *reinterpret_cast<const float4*>(p+4);
  bf16x8 o;
  o[0]=(bf16)va.x; o[1]=(bf16)va.y; o[2]=(bf16)va.z; o[3]=(bf16)va.w;
  o[4]=(bf16)vb.x; o[5]=(bf16)vb.y; o[6]=(bf16)vb.z; o[7]=(bf16)vb.w;
  *reinterpret_cast<bf16x8*>(Xc + e0) = o;
}

// ---- Gc[mg][n] = Xc[mg]·Wt[n] + bias[n]  (fp32 out), mg = b*CHUNK+tt, n = gate*512+d ----
__global__ __launch_bounds__(256) void k_gemmG(const bf16* __restrict__ Xc, const bf16* __restrict__ Wt,
                        const float* __restrict__ bu,const float* __restrict__ br,const float* __restrict__ bh,
                        float* __restrict__ G){
  __shared__ bf16 As[128][40];
  __shared__ bf16 Bs[128][40];
  int m0 = blockIdx.x*128, n0 = blockIdx.y*128;
  int tid = threadIdx.x;
  int w = tid>>6, lane = tid&63;
  int wm = (w&1)*64, wn = (w>>1)*64;
  int lrow = lane&15, lk = (lane>>4)*8;
  f32x4 acc[4][4] = {};
  for (int k0=0;k0<DD;k0+=32){
    for (int p=0;p<2;p++){
      int i = p*256 + tid;
      int r = i>>2, ch = i&3;
      *reinterpret_cast<float4*>(&As[r][ch*8]) =
          *reinterpret_cast<const float4*>(Xc + (size_t)(m0+r)*DD + k0 + ch*8);
      *reinterpret_cast<float4*>(&Bs[r][ch*8]) =
          *reinterpret_cast<const float4*>(Wt + (size_t)(n0+r)*DD + k0 + ch*8);
    }
    __syncthreads();
    bf16x8 a[4], b[4];
    for (int mr=0;mr<4;mr++) a[mr] = *reinterpret_cast<bf16x8*>(&As[wm+mr*16+lrow][lk]);
    for (int nr=0;nr<4;nr++) b[nr] = *reinterpret_cast<bf16x8*>(&Bs[wn+nr*16+lrow][lk]);
    for (int mr=0;mr<4;mr++)
      for (int nr=0;nr<4;nr++)
        acc[mr][nr] = __builtin_amdgcn_mfma_f32_16x16x32_bf16(a[mr], b[nr], acc[mr][nr], 0,0,0);
    __syncthreads();
  }
  for (int nr=0;nr<4;nr++){
    int n = n0 + wn + nr*16 + (lane&15);
    int g = n>>9; int nn = n & 511;
    float bv = (g==0?bu[nn]:g==1?br[nn]:bh[nn]);
    for (int mr=0;mr<4;mr++){
      for (int j=0;j<4;j++){
        int m = m0 + wm + mr*16 + (lane>>4)*4 + j;
        G[(size_t)m*N3 + n] = acc[mr][nr][j] + bv;
      }
    }
  }
}

// ---- one recurrent step: acc = h_prev @ [Uu|Ur|Uh], then gate update ----
__global__ __launch_bounds__(256) void k_step(const bf16* __restrict__ Ut, const float* __restrict__ G,
                       const float* __restrict__ hpf, const bf16* __restrict__ hpb,
                       float* __restrict__ hnf, bf16* __restrict__ hnb,
                       float* __restrict__ out, float* __restrict__ hlast, int t){
  __shared__ bf16 Hs[64][40];
  __shared__ bf16 Us[3][64][40];
  int m0 = blockIdx.x*64, d0 = blockIdx.y*64;
  int tid = threadIdx.x;
  int w = tid>>6, lane = tid&63;
  int wm = (w&1)*32, wd = (w>>1)*32;
  int lrow = lane&15, lk = (lane>>4)*8;
  int tt = t & (CHUNK-1);
  f32x4 acc[3][2][2] = {};
  for (int k0=0;k0<DD;k0+=32){
    { int r = tid>>2, ch = tid&3;
      *reinterpret_cast<float4*>(&Hs[r][ch*8]) =
          *reinterpret_cast<const float4*>(hpb + (size_t)(m0+r)*DD + k0 + ch*8); }
    for (int p=0;p<3;p++){
      int i = p*256 + tid;
      int g = i>>8, r = (i>>2)&63, ch = i&3;
      *reinterpret_cast<float4*>(&Us[g][r][ch*8]) =
          *reinterpret_cast<const float4*>(Ut + (size_t)(g*DD + d0 + r)*DD + k0 + ch*8);
    }
    __syncthreads();
    bf16x8 a[2], b[3][2];
    for (int mr=0;mr<2;mr++) a[mr] = *reinterpret_cast<bf16x8*>(&Hs[wm+mr*16+lrow][lk]);
    for (int g=0;g<3;g++)
      for (int nr=0;nr<2;nr++) b[g][nr] = *reinterpret_cast<bf16x8*>(&Us[g][wd+nr*16+lrow][lk]);
    for (int g=0;g<3;g++)
      for (int mr=0;mr<2;mr++)
        for (int nr=0;nr<2;nr++)
          acc[g][mr][nr] = __builtin_amdgcn_mfma_f32_16x16x32_bf16(a[mr], b[g][nr], acc[g][mr][nr], 0,0,0);
    __syncthreads();
  }
  for (int mr=0;mr<2;mr++) for (int nr=0;nr<2;nr++) for (int j=0;j<4;j++){
    int m = m0 + wm + mr*16 + (lane>>4)*4 + j;      // batch index
    int d = d0 + wd + nr*16 + (lane&15);
    size_t grow = ((size_t)m*CHUNK + tt)*N3;        // chunk-local G row
    float gu = G[grow + d];
    float gr = G[grow + 512 + d];
    float gh = G[grow + 1024 + d];
    float u  = sigm(gu + acc[0][mr][nr][j]);
    float r  = sigm(gr + acc[1][mr][nr][j]);
    float hh = tanhf(gh + r*acc[2][mr][nr][j]);
    float hp = hpf[(size_t)m*DD + d];
    float hn = (1.f-u)*hp + u*hh;
    hnf[(size_t)m*DD + d] = hn;
    hnb[(size_t)m*DD + d] = (bf16)hn;
    out[((size_t)m*SS + t)*DD + d] = hn;
    if (t == SS-1) hlast[(size_t)m*DD + d] = hn;
  }
}

extern "C" void kernel_launch(void* const* d_in, const int* in_sizes, int n_in,
                              void* d_out, int out_size, void* d_ws, size_t ws_size,
                              hipStream_t stream){
  const float* x   = (const float*)d_in[0];
  // d_in[1] = item  (unused: softmax over length-1 axis == 1)
  const float* h0  = (const float*)d_in[2];
  const float* Wu  = (const float*)d_in[3];
  const float* Uu  = (const float*)d_in[4];
  const float* bu  = (const float*)d_in[5];
  const float* Wr  = (const float*)d_in[6];
  const float* Ur  = (const float*)d_in[7];
  const float* br  = (const float*)d_in[8];
  const float* Wh  = (const float*)d_in[9];
  const float* Uh  = (const float*)d_in[10];
  const float* bh  = (const float*)d_in[11];
  // d_in[12] = Wa (unused)
  float* out = (float*)d_out;
  float* hlast = out + (size_t)MTOT*DD;

  char* ws = (char*)d_ws;
  bf16*  Xc  = (bf16*)(ws);                  // 4096x512 bf16 = 4 MB (per-chunk X)
  bf16*  Wt  = (bf16*)(ws + 0x400000);       // 1536x512 bf16 = 1.5 MB
  bf16*  Ut  = (bf16*)(ws + 0x580000);       // 1536x512 bf16 = 1.5 MB
  float* Gc  = (float*)(ws + 0x700000);      // 4096x1536 f32 = 24 MB (per-chunk gates)
  float* hf0 = (float*)(ws + 0x1F00000);     // 256x512 f32
  float* hf1 = (float*)(ws + 0x1F80000);
  bf16*  hb0 = (bf16*)(ws + 0x2000000);      // 256x512 bf16
  bf16*  hb1 = (bf16*)(ws + 0x2040000);      // ends at 0x2080000 = 32.5 MB

  k_transpose<<<dim3(16,16,6), dim3(32,8), 0, stream>>>(Wu,Wr,Wh,Uu,Ur,Uh,Wt,Ut);
  k_init<<<dim3(512), dim3(256), 0, stream>>>(h0, hf0, hf1, hb0, hb1);
  for (int c=0;c<SS/CHUNK;c++){
    k_cvt<<<dim3(MCH*DD/8/256), dim3(256), 0, stream>>>(x, Xc, c*CHUNK);
    k_gemmG<<<dim3(MCH/128,12), dim3(256), 0, stream>>>(Xc, Wt, bu,br,bh, Gc);
    for (int tt=0;tt<CHUNK;tt++){
      int t = c*CHUNK + tt;
      float* hpf = (t&1)? hf1: hf0; float* hnf = (t&1)? hf0: hf1;
      bf16*  hpb = (t&1)? hb1: hb0; bf16*  hnb = (t&1)? hb0: hb1;
      k_step<<<dim3(4,8), dim3(256), 0, stream>>>(Ut, Gc, hpf, hpb, hnf, hnb, out, hlast, t);
    }
  }
}